// Round 7
// baseline (275.771 us; speedup 1.0000x reference)
//
#include <hip/hip_runtime.h>
#include <hip/hip_bf16.h>

#define D 128
#define LR 0.025f
#define NCE_BIAS 11.512925464970229f      // log(100000)
#define NCE_NEG_BIAS 9.903487552536127f   // log(100000/5)
#define LUT_SIZE 1202

__device__ __forceinline__ float wave_allreduce(float x) {
    #pragma unroll
    for (int m = 32; m >= 1; m >>= 1) x += __shfl_xor(x, m, 64);
    return x;
}

// Analytic stand-in for the reference's LUT sigmoid (centered quantization err <=1.25e-3).
__device__ __forceinline__ float fast_sig(float x) {
    x = fminf(fmaxf(x, -6.0f), 6.0f) - 0.005f;
    float e = __expf(-x);
    return __builtin_amdgcn_rcpf(1.0f + e);
}

__device__ __forceinline__ float fast_sig_lut(float s, const float* __restrict__ lut) {
    s = fminf(fmaxf(s, -6.0f), 6.0f);
    int idx = (int)floorf((s + 6.01f) / 0.01f);
    idx = min(max(idx, 0), LUT_SIZE - 1);
    return lut[idx];
}

__device__ __forceinline__ unsigned int bf16_rne(float f) {
    unsigned int u = __float_as_uint(f);
    return (u + 0x7FFFu + ((u >> 16) & 1u)) >> 16;
}

// ---------------- fused prep: W->bf16 shadow + degree histogram ----------------
// cnt2[i] = {pos_degree, neg_degree}. Pos pair t: ONE 64-bit atomic bumps both
// fields of u (pos +1, neg +NEG — idx_neg_u = repeat(idx_pos_u, NEG)).
__global__ __launch_bounds__(256) void prep_kernel(
    const float* __restrict__ W, unsigned short* __restrict__ w16, int n32,
    const int* __restrict__ ipu, const int* __restrict__ ipv,
    const int* __restrict__ inv,
    int Np, int Nn, int NEG, int2* __restrict__ cnt2)
{
    int t = blockIdx.x * 256 + threadIdx.x;
    if (t < n32) {
        float4 v = ((const float4*)W)[t];
        uint2 h;
        h.x = bf16_rne(v.x) | (bf16_rne(v.y) << 16);
        h.y = bf16_rne(v.z) | (bf16_rne(v.w) << 16);
        ((uint2*)w16)[t] = h;
    }
    if (t < Np) {
        atomicAdd((unsigned long long*)&cnt2[ipu[t]],
                  1ull + ((unsigned long long)NEG << 32));
        atomicAdd(&cnt2[ipv[t]].x, 1);
    } else if (t < Np + Nn) {
        int k = t - Np;
        atomicAdd(&cnt2[inv[k]].y, 1);
    }
}

// fused dual exclusive scan (pos & neg fields in one pass)
__global__ __launch_bounds__(256) void scan_local2(
    const int2* __restrict__ cnt2, int* __restrict__ off_p, int* __restrict__ off_n,
    int* __restrict__ bsp, int* __restrict__ bsn, int n)
{
    __shared__ int shp[256], shn[256];
    int g = blockIdx.x * 256 + threadIdx.x;
    int2 x = (g < n) ? cnt2[g] : make_int2(0, 0);
    shp[threadIdx.x] = x.x;
    shn[threadIdx.x] = x.y;
    __syncthreads();
    #pragma unroll
    for (int d = 1; d < 256; d <<= 1) {
        int tp = (threadIdx.x >= d) ? shp[threadIdx.x - d] : 0;
        int tn = (threadIdx.x >= d) ? shn[threadIdx.x - d] : 0;
        __syncthreads();
        shp[threadIdx.x] += tp;
        shn[threadIdx.x] += tn;
        __syncthreads();
    }
    if (g < n) {
        off_p[g] = shp[threadIdx.x] - x.x;
        off_n[g] = shn[threadIdx.x] - x.y;
    }
    if (threadIdx.x == 255) {
        bsp[blockIdx.x] = shp[255];
        bsn[blockIdx.x] = shn[255];
    }
}

__device__ __forceinline__ void scan_one(int* b, int nb) {
    __shared__ int sh[256];
    __shared__ int carry_s;
    if (threadIdx.x == 0) carry_s = 0;
    __syncthreads();
    for (int c = 0; c < nb; c += 256) {
        int i = c + threadIdx.x;
        int x = (i < nb) ? b[i] : 0;
        sh[threadIdx.x] = x;
        __syncthreads();
        for (int d = 1; d < 256; d <<= 1) {
            int t = (threadIdx.x >= d) ? sh[threadIdx.x - d] : 0;
            __syncthreads();
            sh[threadIdx.x] += t;
            __syncthreads();
        }
        int carry = carry_s;
        if (i < nb) b[i] = sh[threadIdx.x] - x + carry;
        __syncthreads();
        if (threadIdx.x == 0) carry_s = carry + sh[255];
        __syncthreads();
    }
}

// block 0 scans bsp, block 1 scans bsn (parallel)
__global__ __launch_bounds__(256) void scan_bsum2(int* __restrict__ bsp, int* __restrict__ bsn, int nb)
{
    scan_one(blockIdx.x == 0 ? bsp : bsn, nb);
}

__global__ __launch_bounds__(256) void add_base2(
    int* __restrict__ off_p, int* __restrict__ off_n, int2* __restrict__ cur2,
    const int* __restrict__ bsp, const int* __restrict__ bsn, int n)
{
    int g = blockIdx.x * 256 + threadIdx.x;
    if (g < n) {
        int vp = off_p[g] + bsp[blockIdx.x];
        int vn = off_n[g] + bsn[blockIdx.x];
        off_p[g] = vp;
        off_n[g] = vn;
        cur2[g] = make_int2(vp, vn);
    }
}

// pos pair t: ONE 64-bit atomic reserves the u-side pos slot AND NEG contiguous
// neg slots; neg partners written contiguously.
__global__ __launch_bounds__(256) void fill_kernel(
    const int* __restrict__ ipu, const int* __restrict__ ipv,
    const int* __restrict__ inu, const int* __restrict__ inv,
    int Np, int Nn, int NEG,
    int2* __restrict__ cur2, int* __restrict__ ent_p, int* __restrict__ ent_n)
{
    int t = blockIdx.x * 256 + threadIdx.x;
    if (t < Np) {
        int u = ipu[t], v = ipv[t];
        unsigned long long pk = atomicAdd((unsigned long long*)&cur2[u],
                                          1ull + ((unsigned long long)NEG << 32));
        int slot_pu = (int)(pk & 0xFFFFFFFFull);
        int slot_nu = (int)(pk >> 32);
        ent_p[slot_pu] = v;
        for (int j = 0; j < NEG; ++j)
            ent_n[slot_nu + j] = inv[(size_t)NEG * t + j];
        ent_p[atomicAdd(&cur2[v].x, 1)] = u;
    } else if (t < Np + Nn) {
        int k = t - Np;
        ent_n[atomicAdd(&cur2[inv[k]].y, 1)] = inu[k];
    }
}

// ---------------- pull update (depth-2 software pipeline) ----------------
// Half-wave per node (32 lanes x float4 base). Partners bf16 (256B rows).
// Entry ids live in a register chunk (32 per coalesced load, __shfl broadcast);
// partner rows prefetched 2 groups ahead via A/B buffers (8 loads in flight).

__device__ __forceinline__ void advance_chunk(
    const int* __restrict__ entries, int beg, int len, int t,
    int& c0, int& e, int hl)
{
    int c0n = (min(t * 4, len - 1) >> 5) << 5;
    if (c0n > c0) {
        c0 = c0n;
        e = entries[beg + min(c0 + hl, len - 1)];
    }
}

__device__ __forceinline__ void load_rows(
    const uint2* __restrict__ ph, int hl, int e, int c0, int t, int len, uint2 r[4])
{
    #pragma unroll
    for (int i = 0; i < 4; ++i) {
        int idx = min(t * 4 + i, len - 1) - c0;     // in [0,32); groups never straddle chunks
        int p = __shfl(e, idx, 32);
        r[i] = ph[(size_t)p * 32 + hl];
    }
}

template<bool EMIT16>
__global__ __launch_bounds__(256) void update_kernel(
    const float* __restrict__ baseSrc,
    const unsigned short* __restrict__ partnerH,
    float* __restrict__ dst, unsigned short* __restrict__ dst16,
    const int* __restrict__ offArr, const int* __restrict__ endArr2, int comp,
    const int* __restrict__ entries, int N, float bias, float cpos)
{
    int gtid = blockIdx.x * 256 + threadIdx.x;
    int node = gtid >> 5;
    int hl   = threadIdx.x & 31;
    if (node >= N) return;

    float4 base = ((const float4*)baseSrc)[(size_t)node * 32 + hl];
    float ax = 0.0f, ay = 0.0f, az = 0.0f, aw = 0.0f;

    int beg = offArr[node];
    int len = endArr2[2 * node + comp] - beg;
    const uint2* ph = (const uint2*)partnerH;

    if (len > 0) {
        int G = (len + 3) >> 2;
        int c0 = 0;
        int e = entries[beg + min(hl, len - 1)];
        uint2 A[4], B[4];
        load_rows(ph, hl, e, c0, 0, len, A);                  // rows g=0
        load_rows(ph, hl, e, c0, 1, len, B);                  // rows g=1 (t=1*4=4 < 32)

        #define STEP(BUF, G_IDX)                                               \
        {                                                                      \
            int gg = (G_IDX);                                                  \
            float4 r[4]; float d[4];                                           \
            _Pragma("unroll")                                                  \
            for (int i = 0; i < 4; ++i) {                                      \
                r[i].x = __uint_as_float(BUF[i].x << 16);                      \
                r[i].y = __uint_as_float(BUF[i].x & 0xFFFF0000u);              \
                r[i].z = __uint_as_float(BUF[i].y << 16);                      \
                r[i].w = __uint_as_float(BUF[i].y & 0xFFFF0000u);              \
                d[i] = r[i].x * base.x + r[i].y * base.y                       \
                     + r[i].z * base.z + r[i].w * base.w;                      \
            }                                                                  \
            _Pragma("unroll")                                                  \
            for (int m = 16; m >= 1; m >>= 1) {                                \
                _Pragma("unroll")                                              \
                for (int i = 0; i < 4; ++i) d[i] += __shfl_xor(d[i], m, 64);   \
            }                                                                  \
            _Pragma("unroll")                                                  \
            for (int i = 0; i < 4; ++i) {                                      \
                float s = (gg * 4 + i < len)                                   \
                        ? (cpos - fast_sig(d[i] - bias)) * LR : 0.0f;          \
                ax += s * r[i].x;                                              \
                ay += s * r[i].y;                                              \
                az += s * r[i].z;                                              \
                aw += s * r[i].w;                                              \
            }                                                                  \
            int t2 = gg + 2;                                                   \
            if (t2 < G) {                                                      \
                advance_chunk(entries, beg, len, t2, c0, e, hl);               \
                load_rows(ph, hl, e, c0, t2, len, BUF);                        \
            }                                                                  \
        }

        for (int g = 0; g < G; g += 2) {
            STEP(A, g);
            if (g + 1 < G) STEP(B, g + 1);
        }
        #undef STEP
    }
    float4 o = make_float4(base.x + ax, base.y + ay, base.z + az, base.w + aw);
    ((float4*)dst)[(size_t)node * 32 + hl] = o;
    if (EMIT16) {
        uint2 h;
        h.x = bf16_rne(o.x) | (bf16_rne(o.y) << 16);
        h.y = bf16_rne(o.z) | (bf16_rne(o.w) << 16);
        ((uint2*)dst16)[(size_t)node * 32 + hl] = h;
    }
}

// ---------------- fallback scatter path (round-1, known-good) ----------------
__global__ __launch_bounds__(256) void pos_kernel(
    const float* __restrict__ Worig, float* __restrict__ W,
    const float* __restrict__ lut,
    const int* __restrict__ idx_u, const int* __restrict__ idx_v, int n)
{
    int wave = (int)((blockIdx.x * blockDim.x + threadIdx.x) >> 6);
    int lane = threadIdx.x & 63;
    if (wave >= n) return;
    int u = idx_u[wave];
    int v = idx_v[wave];
    float2 eu = ((const float2*)(Worig + (size_t)u * D))[lane];
    float2 ev = ((const float2*)(Worig + (size_t)v * D))[lane];
    float dot = wave_allreduce(eu.x * ev.x + eu.y * ev.y);
    float s = (1.0f - fast_sig_lut(dot - NCE_BIAS, lut)) * LR;
    float* wu = W + (size_t)u * D;
    float* wv = W + (size_t)v * D;
    atomicAdd(&wu[2 * lane],     s * ev.x);
    atomicAdd(&wu[2 * lane + 1], s * ev.y);
    atomicAdd(&wv[2 * lane],     s * eu.x);
    atomicAdd(&wv[2 * lane + 1], s * eu.y);
}

__global__ __launch_bounds__(256) void neg_kernel(
    const float* __restrict__ Wsnap, float* __restrict__ W,
    const float* __restrict__ lut,
    const int* __restrict__ idx_u, const int* __restrict__ idx_v, int n, int neg)
{
    int wave = (int)((blockIdx.x * blockDim.x + threadIdx.x) >> 6);
    int lane = threadIdx.x & 63;
    if (wave >= n) return;
    int u = idx_u[wave * neg];
    float2 eu = ((const float2*)(Wsnap + (size_t)u * D))[lane];
    float dux = 0.0f, duy = 0.0f;
    for (int j = 0; j < neg; ++j) {
        int v = idx_v[wave * neg + j];
        float2 ev = ((const float2*)(Wsnap + (size_t)v * D))[lane];
        float dot = wave_allreduce(eu.x * ev.x + eu.y * ev.y);
        float s = -fast_sig_lut(dot - NCE_NEG_BIAS, lut) * LR;
        dux += s * ev.x;
        duy += s * ev.y;
        float* wv = W + (size_t)v * D;
        atomicAdd(&wv[2 * lane],     s * eu.x);
        atomicAdd(&wv[2 * lane + 1], s * eu.y);
    }
    float* wu = W + (size_t)u * D;
    atomicAdd(&wu[2 * lane],     dux);
    atomicAdd(&wu[2 * lane + 1], duy);
}

extern "C" void kernel_launch(void* const* d_in, const int* in_sizes, int n_in,
                              void* d_out, int out_size, void* d_ws, size_t ws_size,
                              hipStream_t stream) {
    const float* W   = (const float*)d_in[0];
    const float* lut = (const float*)d_in[1];
    const int* ipu   = (const int*)d_in[2];
    const int* ipv   = (const int*)d_in[3];
    const int* inu   = (const int*)d_in[4];
    const int* inv   = (const int*)d_in[5];
    float* out = (float*)d_out;

    const int N  = in_sizes[0] / D;        // nodes
    const int Np = in_sizes[2];            // positive pairs
    const int Nn = in_sizes[4];            // negative pairs (N*NEG)
    const int NEG = Nn / Np;
    const size_t WB = (size_t)N * D * sizeof(float);
    const int nb = (N + 255) / 256;
    const int n_entp = 2 * Np;
    const int n_entn = NEG * Np + Nn;

    size_t need = (size_t)N * D * 2 * 2                       // w16W + w16P
                + (size_t)n_entp * 4 + (size_t)n_entn * 4
                + (size_t)N * 8 * 2 + (size_t)N * 4 * 2       // cnt2, cur2, off_p, off_n
                + (size_t)nb * 4 * 2 + 64;

    if (ws_size >= need) {
        char* p = (char*)d_ws;
        unsigned short* w16W = (unsigned short*)p; p += (size_t)N * D * 2;
        unsigned short* w16P = (unsigned short*)p; p += (size_t)N * D * 2;
        int*  ent_p = (int*)p;  p += (size_t)n_entp * 4;
        int*  ent_n = (int*)p;  p += (size_t)n_entn * 4;
        int2* cnt2  = (int2*)p; p += (size_t)N * 8;
        int2* cur2  = (int2*)p; p += (size_t)N * 8;
        int*  off_p = (int*)p;  p += (size_t)N * 4;
        int*  off_n = (int*)p;  p += (size_t)N * 4;
        int*  bsp   = (int*)p;  p += (size_t)nb * 4;
        int*  bsn   = (int*)p;

        hipMemsetAsync(cnt2, 0, (size_t)N * 8, stream);
        int n32 = N * 32;
        int tot = Np + Nn;
        int pgrid = (max(n32, tot) + 255) / 256;
        prep_kernel<<<pgrid, 256, 0, stream>>>(W, w16W, n32, ipu, ipv, inv, Np, Nn, NEG, cnt2);
        scan_local2<<<nb, 256, 0, stream>>>(cnt2, off_p, off_n, bsp, bsn, N);
        scan_bsum2<<<2, 256, 0, stream>>>(bsp, bsn, nb);
        add_base2<<<nb, 256, 0, stream>>>(off_p, off_n, cur2, bsp, bsn, N);
        fill_kernel<<<(tot + 255) / 256, 256, 0, stream>>>(ipu, ipv, inu, inv, Np, Nn, NEG,
                                                           cur2, ent_p, ent_n);

        int ublocks = (n32 + 255) / 256;
        // pos: base=W fp32, partners=bf16(W); write Wpos fp32 -> d_out + bf16 shadow -> w16P
        update_kernel<true><<<ublocks, 256, 0, stream>>>(
            W, w16W, out, w16P, off_p, (const int*)cur2, 0, ent_p, N, NCE_BIAS, 1.0f);
        // neg: base=own fp32 row of d_out (Wpos), partners=bf16(Wpos); overwrite own row
        update_kernel<false><<<ublocks, 256, 0, stream>>>(
            out, w16P, out, (unsigned short*)nullptr, off_n, (const int*)cur2, 1, ent_n,
            N, NCE_NEG_BIAS, 0.0f);
    } else {
        // scatter fallback (needs only one W-sized snapshot)
        float* snap = (float*)d_ws;
        hipMemcpyAsync(out, W, WB, hipMemcpyDeviceToDevice, stream);
        int blocks = (Np * 64 + 255) / 256;
        pos_kernel<<<blocks, 256, 0, stream>>>(W, out, lut, ipu, ipv, Np);
        hipMemcpyAsync(snap, out, WB, hipMemcpyDeviceToDevice, stream);
        neg_kernel<<<blocks, 256, 0, stream>>>(snap, out, lut, inu, inv, Np, NEG);
    }
}

// Round 8
// 275.517 us; speedup vs baseline: 1.0009x; 1.0009x over previous
//
#include <hip/hip_runtime.h>
#include <hip/hip_bf16.h>

#define D 128
#define LR 0.025f
#define NCE_BIAS 11.512925464970229f      // log(100000)
#define NCE_NEG_BIAS 9.903487552536127f   // log(100000/5)
#define LUT_SIZE 1202
#define LOG2E 1.4426950408889634f

__device__ __forceinline__ float wave_allreduce(float x) {
    #pragma unroll
    for (int m = 32; m >= 1; m >>= 1) x += __shfl_xor(x, m, 64);
    return x;
}

__device__ __forceinline__ float fast_sig_lut(float s, const float* __restrict__ lut) {
    s = fminf(fmaxf(s, -6.0f), 6.0f);
    int idx = (int)floorf((s + 6.01f) / 0.01f);
    idx = min(max(idx, 0), LUT_SIZE - 1);
    return lut[idx];
}

__device__ __forceinline__ unsigned int bf16_rne(float f) {
    unsigned int u = __float_as_uint(f);
    return (u + 0x7FFFu + ((u >> 16) & 1u)) >> 16;
}

// ---------------- fused prep: W->bf16 shadow + degree histogram ----------------
// cnt2[i] = {pos_degree, neg_degree}. Pos pair t: ONE 64-bit atomic bumps both
// fields of u (pos +1, neg +NEG — idx_neg_u = repeat(idx_pos_u, NEG)).
__global__ __launch_bounds__(256) void prep_kernel(
    const float* __restrict__ W, unsigned short* __restrict__ w16, int n32,
    const int* __restrict__ ipu, const int* __restrict__ ipv,
    const int* __restrict__ inv,
    int Np, int Nn, int NEG, int2* __restrict__ cnt2)
{
    int t = blockIdx.x * 256 + threadIdx.x;
    if (t < n32) {
        float4 v = ((const float4*)W)[t];
        uint2 h;
        h.x = bf16_rne(v.x) | (bf16_rne(v.y) << 16);
        h.y = bf16_rne(v.z) | (bf16_rne(v.w) << 16);
        ((uint2*)w16)[t] = h;
    }
    if (t < Np) {
        atomicAdd((unsigned long long*)&cnt2[ipu[t]],
                  1ull + ((unsigned long long)NEG << 32));
        atomicAdd(&cnt2[ipv[t]].x, 1);
    } else if (t < Np + Nn) {
        int k = t - Np;
        atomicAdd(&cnt2[inv[k]].y, 1);
    }
}

// fused dual exclusive scan (pos & neg fields in one pass)
__global__ __launch_bounds__(256) void scan_local2(
    const int2* __restrict__ cnt2, int* __restrict__ off_p, int* __restrict__ off_n,
    int* __restrict__ bsp, int* __restrict__ bsn, int n)
{
    __shared__ int shp[256], shn[256];
    int g = blockIdx.x * 256 + threadIdx.x;
    int2 x = (g < n) ? cnt2[g] : make_int2(0, 0);
    shp[threadIdx.x] = x.x;
    shn[threadIdx.x] = x.y;
    __syncthreads();
    #pragma unroll
    for (int d = 1; d < 256; d <<= 1) {
        int tp = (threadIdx.x >= d) ? shp[threadIdx.x - d] : 0;
        int tn = (threadIdx.x >= d) ? shn[threadIdx.x - d] : 0;
        __syncthreads();
        shp[threadIdx.x] += tp;
        shn[threadIdx.x] += tn;
        __syncthreads();
    }
    if (g < n) {
        off_p[g] = shp[threadIdx.x] - x.x;
        off_n[g] = shn[threadIdx.x] - x.y;
    }
    if (threadIdx.x == 255) {
        bsp[blockIdx.x] = shp[255];
        bsn[blockIdx.x] = shn[255];
    }
}

__device__ __forceinline__ void scan_one(int* b, int nb) {
    __shared__ int sh[256];
    __shared__ int carry_s;
    if (threadIdx.x == 0) carry_s = 0;
    __syncthreads();
    for (int c = 0; c < nb; c += 256) {
        int i = c + threadIdx.x;
        int x = (i < nb) ? b[i] : 0;
        sh[threadIdx.x] = x;
        __syncthreads();
        for (int d = 1; d < 256; d <<= 1) {
            int t = (threadIdx.x >= d) ? sh[threadIdx.x - d] : 0;
            __syncthreads();
            sh[threadIdx.x] += t;
            __syncthreads();
        }
        int carry = carry_s;
        if (i < nb) b[i] = sh[threadIdx.x] - x + carry;
        __syncthreads();
        if (threadIdx.x == 0) carry_s = carry + sh[255];
        __syncthreads();
    }
}

// block 0 scans bsp, block 1 scans bsn (parallel)
__global__ __launch_bounds__(256) void scan_bsum2(int* __restrict__ bsp, int* __restrict__ bsn, int nb)
{
    scan_one(blockIdx.x == 0 ? bsp : bsn, nb);
}

__global__ __launch_bounds__(256) void add_base2(
    int* __restrict__ off_p, int* __restrict__ off_n, int2* __restrict__ cur2,
    const int* __restrict__ bsp, const int* __restrict__ bsn, int n)
{
    int g = blockIdx.x * 256 + threadIdx.x;
    if (g < n) {
        int vp = off_p[g] + bsp[blockIdx.x];
        int vn = off_n[g] + bsn[blockIdx.x];
        off_p[g] = vp;
        off_n[g] = vn;
        cur2[g] = make_int2(vp, vn);
    }
}

// pos pair t: ONE 64-bit atomic reserves the u-side pos slot AND NEG contiguous
// neg slots; neg partners written contiguously.
__global__ __launch_bounds__(256) void fill_kernel(
    const int* __restrict__ ipu, const int* __restrict__ ipv,
    const int* __restrict__ inu, const int* __restrict__ inv,
    int Np, int Nn, int NEG,
    int2* __restrict__ cur2, int* __restrict__ ent_p, int* __restrict__ ent_n)
{
    int t = blockIdx.x * 256 + threadIdx.x;
    if (t < Np) {
        int u = ipu[t], v = ipv[t];
        unsigned long long pk = atomicAdd((unsigned long long*)&cur2[u],
                                          1ull + ((unsigned long long)NEG << 32));
        int slot_pu = (int)(pk & 0xFFFFFFFFull);
        int slot_nu = (int)(pk >> 32);
        ent_p[slot_pu] = v;
        for (int j = 0; j < NEG; ++j)
            ent_n[slot_nu + j] = inv[(size_t)NEG * t + j];
        ent_p[atomicAdd(&cur2[v].x, 1)] = u;
    } else if (t < Np + Nn) {
        int k = t - Np;
        ent_n[atomicAdd(&cur2[inv[k]].y, 1)] = inu[k];
    }
}

// ---------------- pull update: 16 lanes per node, 8 elems/lane ----------------
// One uint4 (8 bf16) per lane = whole 256B partner row per coalesced dwordx4.
// 4-step butterfly (masks <=8 stay within the 16-lane group). 4 partners per
// iteration, rows prefetched 1 group ahead, entries 2 ahead (R6's proven depth).
// Sigmoid folded: s = scale * rcp(1 + exp2(kk*y + c0)), y=clip(dot-bias), c0=-0.005*kk.
template<bool EMIT16>
__global__ __launch_bounds__(256) void update_kernel(
    const float* __restrict__ baseSrc,
    const unsigned short* __restrict__ partnerH,
    float* __restrict__ dst, unsigned short* __restrict__ dst16,
    const int* __restrict__ offArr, const int* __restrict__ endArr2, int comp,
    const int* __restrict__ entries, int N, float bias, float scale, float kk)
{
    int gtid = blockIdx.x * 256 + threadIdx.x;
    int node = gtid >> 4;
    int l16  = threadIdx.x & 15;
    if (node >= N) return;

    const float4* bp = (const float4*)baseSrc;
    float4 b0 = bp[(size_t)node * 32 + 2 * l16];
    float4 b1 = bp[(size_t)node * 32 + 2 * l16 + 1];
    float4 a0 = make_float4(0.f, 0.f, 0.f, 0.f);
    float4 a1 = make_float4(0.f, 0.f, 0.f, 0.f);

    int beg = offArr[node];
    int len = endArr2[2 * node + comp] - beg;
    const uint4* ph = (const uint4*)partnerH;
    const float c0 = -0.005f * kk;

    if (len > 0) {
        int G = (len + 3) >> 2;
        int en[4];
        uint4 rc[4];
        #pragma unroll
        for (int i = 0; i < 4; ++i)
            rc[i] = ph[(size_t)entries[beg + min(i, len - 1)] * 16 + l16];
        #pragma unroll
        for (int i = 0; i < 4; ++i)
            en[i] = entries[beg + min(4 + i, len - 1)];

        for (int g = 0; g < G; ++g) {
            uint4 rn[4];
            #pragma unroll
            for (int i = 0; i < 4; ++i) rn[i] = ph[(size_t)en[i] * 16 + l16];
            int en2[4];
            #pragma unroll
            for (int i = 0; i < 4; ++i)
                en2[i] = entries[beg + min((g + 2) * 4 + i, len - 1)];

            float4 r0[4], r1[4];
            float d[4];
            #pragma unroll
            for (int i = 0; i < 4; ++i) {
                r0[i].x = __uint_as_float(rc[i].x << 16);
                r0[i].y = __uint_as_float(rc[i].x & 0xFFFF0000u);
                r0[i].z = __uint_as_float(rc[i].y << 16);
                r0[i].w = __uint_as_float(rc[i].y & 0xFFFF0000u);
                r1[i].x = __uint_as_float(rc[i].z << 16);
                r1[i].y = __uint_as_float(rc[i].z & 0xFFFF0000u);
                r1[i].z = __uint_as_float(rc[i].w << 16);
                r1[i].w = __uint_as_float(rc[i].w & 0xFFFF0000u);
                d[i] = r0[i].x * b0.x + r0[i].y * b0.y + r0[i].z * b0.z + r0[i].w * b0.w
                     + r1[i].x * b1.x + r1[i].y * b1.y + r1[i].z * b1.z + r1[i].w * b1.w;
            }
            #pragma unroll
            for (int m = 8; m >= 1; m >>= 1) {
                #pragma unroll
                for (int i = 0; i < 4; ++i) d[i] += __shfl_xor(d[i], m, 64);
            }
            #pragma unroll
            for (int i = 0; i < 4; ++i) {
                float y = fminf(fmaxf(d[i] - bias, -6.0f), 6.0f);
                float s = scale * __builtin_amdgcn_rcpf(1.0f + exp2f(fmaf(kk, y, c0)));
                s = (g * 4 + i < len) ? s : 0.0f;
                a0.x += s * r0[i].x; a0.y += s * r0[i].y;
                a0.z += s * r0[i].z; a0.w += s * r0[i].w;
                a1.x += s * r1[i].x; a1.y += s * r1[i].y;
                a1.z += s * r1[i].z; a1.w += s * r1[i].w;
            }
            #pragma unroll
            for (int i = 0; i < 4; ++i) { rc[i] = rn[i]; en[i] = en2[i]; }
        }
    }
    float4 o0 = make_float4(b0.x + a0.x, b0.y + a0.y, b0.z + a0.z, b0.w + a0.w);
    float4 o1 = make_float4(b1.x + a1.x, b1.y + a1.y, b1.z + a1.z, b1.w + a1.w);
    ((float4*)dst)[(size_t)node * 32 + 2 * l16]     = o0;
    ((float4*)dst)[(size_t)node * 32 + 2 * l16 + 1] = o1;
    if (EMIT16) {
        uint4 h;
        h.x = bf16_rne(o0.x) | (bf16_rne(o0.y) << 16);
        h.y = bf16_rne(o0.z) | (bf16_rne(o0.w) << 16);
        h.z = bf16_rne(o1.x) | (bf16_rne(o1.y) << 16);
        h.w = bf16_rne(o1.z) | (bf16_rne(o1.w) << 16);
        ((uint4*)dst16)[(size_t)node * 16 + l16] = h;
    }
}

// ---------------- fallback scatter path (round-1, known-good) ----------------
__global__ __launch_bounds__(256) void pos_kernel(
    const float* __restrict__ Worig, float* __restrict__ W,
    const float* __restrict__ lut,
    const int* __restrict__ idx_u, const int* __restrict__ idx_v, int n)
{
    int wave = (int)((blockIdx.x * blockDim.x + threadIdx.x) >> 6);
    int lane = threadIdx.x & 63;
    if (wave >= n) return;
    int u = idx_u[wave];
    int v = idx_v[wave];
    float2 eu = ((const float2*)(Worig + (size_t)u * D))[lane];
    float2 ev = ((const float2*)(Worig + (size_t)v * D))[lane];
    float dot = wave_allreduce(eu.x * ev.x + eu.y * ev.y);
    float s = (1.0f - fast_sig_lut(dot - NCE_BIAS, lut)) * LR;
    float* wu = W + (size_t)u * D;
    float* wv = W + (size_t)v * D;
    atomicAdd(&wu[2 * lane],     s * ev.x);
    atomicAdd(&wu[2 * lane + 1], s * ev.y);
    atomicAdd(&wv[2 * lane],     s * eu.x);
    atomicAdd(&wv[2 * lane + 1], s * eu.y);
}

__global__ __launch_bounds__(256) void neg_kernel(
    const float* __restrict__ Wsnap, float* __restrict__ W,
    const float* __restrict__ lut,
    const int* __restrict__ idx_u, const int* __restrict__ idx_v, int n, int neg)
{
    int wave = (int)((blockIdx.x * blockDim.x + threadIdx.x) >> 6);
    int lane = threadIdx.x & 63;
    if (wave >= n) return;
    int u = idx_u[wave * neg];
    float2 eu = ((const float2*)(Wsnap + (size_t)u * D))[lane];
    float dux = 0.0f, duy = 0.0f;
    for (int j = 0; j < neg; ++j) {
        int v = idx_v[wave * neg + j];
        float2 ev = ((const float2*)(Wsnap + (size_t)v * D))[lane];
        float dot = wave_allreduce(eu.x * ev.x + eu.y * ev.y);
        float s = -fast_sig_lut(dot - NCE_NEG_BIAS, lut) * LR;
        dux += s * ev.x;
        duy += s * ev.y;
        float* wv = W + (size_t)v * D;
        atomicAdd(&wv[2 * lane],     s * eu.x);
        atomicAdd(&wv[2 * lane + 1], s * eu.y);
    }
    float* wu = W + (size_t)u * D;
    atomicAdd(&wu[2 * lane],     dux);
    atomicAdd(&wu[2 * lane + 1], duy);
}

extern "C" void kernel_launch(void* const* d_in, const int* in_sizes, int n_in,
                              void* d_out, int out_size, void* d_ws, size_t ws_size,
                              hipStream_t stream) {
    const float* W   = (const float*)d_in[0];
    const float* lut = (const float*)d_in[1];
    const int* ipu   = (const int*)d_in[2];
    const int* ipv   = (const int*)d_in[3];
    const int* inu   = (const int*)d_in[4];
    const int* inv   = (const int*)d_in[5];
    float* out = (float*)d_out;

    const int N  = in_sizes[0] / D;        // nodes
    const int Np = in_sizes[2];            // positive pairs
    const int Nn = in_sizes[4];            // negative pairs (N*NEG)
    const int NEG = Nn / Np;
    const size_t WB = (size_t)N * D * sizeof(float);
    const int nb = (N + 255) / 256;
    const int n_entp = 2 * Np;
    const int n_entn = NEG * Np + Nn;

    size_t need = (size_t)N * D * 2 * 2                       // w16W + w16P
                + (size_t)n_entp * 4 + (size_t)n_entn * 4
                + (size_t)N * 8 * 2 + (size_t)N * 4 * 2       // cnt2, cur2, off_p, off_n
                + (size_t)nb * 4 * 2 + 64;

    if (ws_size >= need) {
        char* p = (char*)d_ws;
        unsigned short* w16W = (unsigned short*)p; p += (size_t)N * D * 2;
        unsigned short* w16P = (unsigned short*)p; p += (size_t)N * D * 2;
        int*  ent_p = (int*)p;  p += (size_t)n_entp * 4;
        int*  ent_n = (int*)p;  p += (size_t)n_entn * 4;
        int2* cnt2  = (int2*)p; p += (size_t)N * 8;
        int2* cur2  = (int2*)p; p += (size_t)N * 8;
        int*  off_p = (int*)p;  p += (size_t)N * 4;
        int*  off_n = (int*)p;  p += (size_t)N * 4;
        int*  bsp   = (int*)p;  p += (size_t)nb * 4;
        int*  bsn   = (int*)p;

        hipMemsetAsync(cnt2, 0, (size_t)N * 8, stream);
        int n32 = N * 32;
        int tot = Np + Nn;
        int pgrid = (max(n32, tot) + 255) / 256;
        prep_kernel<<<pgrid, 256, 0, stream>>>(W, w16W, n32, ipu, ipv, inv, Np, Nn, NEG, cnt2);
        scan_local2<<<nb, 256, 0, stream>>>(cnt2, off_p, off_n, bsp, bsn, N);
        scan_bsum2<<<2, 256, 0, stream>>>(bsp, bsn, nb);
        add_base2<<<nb, 256, 0, stream>>>(off_p, off_n, cur2, bsp, bsn, N);
        fill_kernel<<<(tot + 255) / 256, 256, 0, stream>>>(ipu, ipv, inu, inv, Np, Nn, NEG,
                                                           cur2, ent_p, ent_n);

        int ublocks = (N * 16 + 255) / 256;   // one 16-lane group per node
        // pos: base=W fp32, partners=bf16(W); write Wpos fp32 -> d_out + bf16 shadow -> w16P
        update_kernel<true><<<ublocks, 256, 0, stream>>>(
            W, w16W, out, w16P, off_p, (const int*)cur2, 0, ent_p,
            N, NCE_BIAS, LR, LOG2E);
        // neg: base=own fp32 row of d_out (Wpos), partners=bf16(Wpos); overwrite own row
        update_kernel<false><<<ublocks, 256, 0, stream>>>(
            out, w16P, out, (unsigned short*)nullptr, off_n, (const int*)cur2, 1, ent_n,
            N, NCE_NEG_BIAS, -LR, -LOG2E);
    } else {
        // scatter fallback (needs only one W-sized snapshot)
        float* snap = (float*)d_ws;
        hipMemcpyAsync(out, W, WB, hipMemcpyDeviceToDevice, stream);
        int blocks = (Np * 64 + 255) / 256;
        pos_kernel<<<blocks, 256, 0, stream>>>(W, out, lut, ipu, ipv, Np);
        hipMemcpyAsync(snap, out, WB, hipMemcpyDeviceToDevice, stream);
        neg_kernel<<<blocks, 256, 0, stream>>>(snap, out, lut, inu, inv, Np, NEG);
    }
}